// Round 9
// baseline (136.039 us; speedup 1.0000x reference)
//
#include <hip/hip_runtime.h>
#include <hip/hip_bf16.h>

#define E_EDGES 300000
#define N_NODES 50000
#define BE 256              // edges per block (4 waves x 64)
#define NT 256
#define NCH 64              // 64 chunks x 64 K-depth = 4096
#define CHB 4096            // chunk bytes: 32 v * 64 k * 2B
#define BIAS_OFF 262144     // b2 image (2 KB)
#define W1PK_OFF 264192     // W1 dup-f16 image (3 KB)
#define B1PK_OFF 267264     // b1 dup-f16 image (512 B)

typedef _Float16 h2 __attribute__((ext_vector_type(2)));
typedef _Float16 h8 __attribute__((ext_vector_type(8)));
typedef float f32x16 __attribute__((ext_vector_type(16)));

static __device__ __forceinline__ unsigned short f2h(float f) {
  _Float16 h = (_Float16)f;
  return __builtin_bit_cast(unsigned short, h);
}
static __device__ __forceinline__ h2 cvt2(float a, float b) {
  auto r = __builtin_amdgcn_cvt_pkrtz(a, b);
  return __builtin_bit_cast(h2, r);
}
static __device__ __forceinline__ h2 bc(unsigned u) { return __builtin_bit_cast(h2, u); }
static __device__ __forceinline__ h2 dup_lo(h2 p) { return (h2){p[0], p[0]}; }
static __device__ __forceinline__ h2 dup_hi(h2 p) { return (h2){p[1], p[1]}; }
// A-fragment = hd (broadcast h) * 4 packed x pairs -> 4 v_pk_mul_f16
static __device__ __forceinline__ h8 mk4(h2 hd, const h2* p) {
  h2 m0 = hd * p[0], m1 = hd * p[1], m2 = hd * p[2], m3 = hd * p[3];
  return (h8){m0[0], m0[1], m1[0], m1[1], m2[0], m2[1], m3[0], m3[1]};
}
static __device__ __forceinline__ h8 pk4(const h2* p) {
  return (h8){p[0][0], p[0][1], p[1][0], p[1][1], p[2][0], p[2][1], p[3][0], p[3][1]};
}

// ---------------------------------------------------------------------------
// Prep: W2 (flat (4096,32) row-major) -> f16, transposed [v][k] per 64-deep
// chunk (4 KB images: 32 v-rows x 128 B), XOR-swizzled ((v&7)<<4 on 16B
// granules within each 128B row). b2 -> [v][w] f16 image. W1/b1 -> dup-f16.
// ---------------------------------------------------------------------------
__global__ void prep_w2t(const float* __restrict__ W2, const float* __restrict__ b2,
                         const float* __restrict__ W1, const float* __restrict__ b1,
                         char* __restrict__ ws) {
  int tid = blockIdx.x * 256 + threadIdx.x;
  if (tid < 65536) {                  // 64 chunks * 32 v * 32 k-pairs
    int c   = tid >> 10;
    int rem = tid & 1023;
    int v   = rem >> 5;               // 0..31
    int kp  = rem & 31;               // k-pair within chunk
    int kg2 = c * 64 + kp * 2;        // global K index
    unsigned u = (unsigned)f2h(W2[(size_t)kg2 * 32 + v]) |
                 ((unsigned)f2h(W2[(size_t)(kg2 + 1) * 32 + v]) << 16);
    int off = c * CHB + v * 128 + ((kp * 4) ^ ((v & 7) << 4));
    *(unsigned*)(ws + off) = u;
  } else if (tid < 66048) {           // bias b2: 32 v * 16 w-pairs
    int i  = tid - 65536;
    int v  = i & 31;
    int wp = i >> 5;
    int w  = wp * 2;
    unsigned u = (unsigned)f2h(b2[w * 32 + v]) |
                 ((unsigned)f2h(b2[(w + 1) * 32 + v]) << 16);
    *(unsigned*)(ws + BIAS_OFF + v * 64 + wp * 4) = u;
  } else if (tid < 66816) {           // W1 dup image: 6*128
    int i = tid - 66048;
    unsigned short s = f2h(W1[i]);
    *(unsigned*)(ws + W1PK_OFF + i * 4) = (unsigned)s | ((unsigned)s << 16);
  } else if (tid < 66944) {           // b1 dup image: 128
    int i = tid - 66816;
    unsigned short s = f2h(b1[i]);
    *(unsigned*)(ws + B1PK_OFF + i * 4) = (unsigned)s | ((unsigned)s << 16);
  }
}

// ---------------------------------------------------------------------------
// Fused main, ZERO BARRIERS: each wave owns a private double-buffered 2x4KB
// LDS stage of the W2 chunk stream and syncs only on its own vmcnt. Waves are
// fully independent -> no convoy, no phase-locking. Packed-f16 h recompute
// (2 hidden units per chunk) -> pk_mul A-frags -> f16 MFMA -> bias -> scatter.
// ---------------------------------------------------------------------------
__launch_bounds__(NT, 4)
__global__ void nnconv_main(const float* __restrict__ x,
                            const int* __restrict__ senders,
                            const int* __restrict__ receivers,
                            const float* __restrict__ edge_attr,
                            const char* __restrict__ ws,
                            float* __restrict__ out) {
  __shared__ __align__(16) char w2t[4][2][CHB];   // [wave][dbuf][chunk]
  __shared__ int rcv_lds[BE];                     // wave-local slices only

  const int t    = threadIdx.x;
  const int wid  = t >> 6;
  const int lane = t & 63;
  const int col  = lane & 31;
  const int hi   = lane >> 5;
  const int E0   = blockIdx.x * BE;

  char* lds0 = &w2t[wid][0][0];
  char* lds1 = &w2t[wid][1][0];

  // ---- issue private stage of chunk 0 (earliest)
#pragma unroll
  for (int it = 0; it < 4; ++it)
    __builtin_amdgcn_global_load_lds(
        (const __attribute__((address_space(1))) void*)(ws + it * 1024 + lane * 16),
        (__attribute__((address_space(3))) void*)(lds0 + it * 1024 + lane * 16), 16, 0, 0);

  rcv_lds[t] = (E0 + t < E_EDGES) ? receivers[E0 + t] : -1;   // wave-local use

  // ---- this lane's two edge rows
  const int el0 = wid * 64 + col;
  const int el1 = el0 + 32;
  const int ge0 = min(E0 + el0, E_EDGES - 1);
  const int ge1 = min(E0 + el1, E_EDGES - 1);

  // ---- edge attrs for BOTH edges, packed (el0 in lo, el1 in hi)
  h2 ea2[6];
  {
    const float2* p0 = (const float2*)(edge_attr + (size_t)ge0 * 6);
    const float2* p1 = (const float2*)(edge_attr + (size_t)ge1 * 6);
    const float2 a0 = p0[0], a1 = p0[1], a2 = p0[2];
    const float2 c0 = p1[0], c1 = p1[1], c2 = p1[2];
    ea2[0] = cvt2(a0.x, c0.x); ea2[1] = cvt2(a0.y, c0.y);
    ea2[2] = cvt2(a1.x, c1.x); ea2[3] = cvt2(a1.y, c1.y);
    ea2[4] = cvt2(a2.x, c2.x); ea2[5] = cvt2(a2.y, c2.y);
  }

  // ---- gather x_j slices, convert to f16 pairs
  const float* row0 = x + (size_t)senders[ge0] * 32;
  const float* row1 = x + (size_t)senders[ge1] * 32;
  float4 fa, fb;
  fa = *(const float4*)(row0 + hi * 8);      fb = *(const float4*)(row0 + hi * 8 + 4);
  const h2 xA0[4] = {cvt2(fa.x, fa.y), cvt2(fa.z, fa.w), cvt2(fb.x, fb.y), cvt2(fb.z, fb.w)};
  fa = *(const float4*)(row0 + 16 + hi * 8); fb = *(const float4*)(row0 + 16 + hi * 8 + 4);
  const h2 xB0[4] = {cvt2(fa.x, fa.y), cvt2(fa.z, fa.w), cvt2(fb.x, fb.y), cvt2(fb.z, fb.w)};
  fa = *(const float4*)(row1 + hi * 8);      fb = *(const float4*)(row1 + hi * 8 + 4);
  const h2 xA1[4] = {cvt2(fa.x, fa.y), cvt2(fa.z, fa.w), cvt2(fb.x, fb.y), cvt2(fb.z, fb.w)};
  fa = *(const float4*)(row1 + 16 + hi * 8); fb = *(const float4*)(row1 + 16 + hi * 8 + 4);
  const h2 xB1[4] = {cvt2(fa.x, fa.y), cvt2(fa.z, fa.w), cvt2(fb.x, fb.y), cvt2(fb.z, fb.w)};

  const unsigned* w1p = (const unsigned*)(ws + W1PK_OFF);
  const unsigned* b1p = (const unsigned*)(ws + B1PK_OFF);

  f32x16 acc0 = {};
  f32x16 acc1 = {};
  const int swR = (col & 7) << 4;
  int buf = 0;

#pragma unroll 1
  for (int c = 0; c < NCH; ++c) {
    // wave-private wait: chunk c's 4 loads (issued one full chunk ago) done
    asm volatile("s_waitcnt vmcnt(0)" ::: "memory");

    if (c + 1 < NCH) {   // issue next chunk into the other private buffer
      const char* g = ws + (c + 1) * CHB;
      char* l = buf ? lds0 : lds1;
#pragma unroll
      for (int it = 0; it < 4; ++it)
        __builtin_amdgcn_global_load_lds(
            (const __attribute__((address_space(1))) void*)(g + it * 1024 + lane * 16),
            (__attribute__((address_space(3))) void*)(l + it * 1024 + lane * 16), 16, 0, 0);
    }

    // ---- h for hidden units 2c, 2c+1 (both edges packed, uniform loads)
    h2 hv0, hv1;
    {
      const uint2 bq = *(const uint2*)(b1p + c * 2);
      hv0 = bc(bq.x); hv1 = bc(bq.y);
#pragma unroll
      for (int d = 0; d < 6; ++d) {
        const uint2 wq = *(const uint2*)(w1p + d * 128 + c * 2);
        hv0 += ea2[d] * bc(wq.x);
        hv1 += ea2[d] * bc(wq.y);
      }
    }
    hv0 = __builtin_elementwise_max(hv0, (h2)(_Float16)0);
    hv1 = __builtin_elementwise_max(hv1, (h2)(_Float16)0);
    const h2 hA[2] = {dup_lo(hv0), dup_lo(hv1)};
    const h2 hB[2] = {dup_hi(hv0), dup_hi(hv1)};

    // ---- 4 K-steps over this chunk (8 MFMA)
    const char* Bb = (buf ? lds1 : lds0) + col * 128;
#pragma unroll
    for (int s = 0; s < 4; ++s) {
      const h8 B = *(const h8*)(Bb + ((s * 32 + hi * 16) ^ swR));
      const int u = s >> 1;
      h8 A0, A1;
      if (s & 1) { A0 = mk4(hA[u], xB0); A1 = mk4(hB[u], xB1); }
      else       { A0 = mk4(hA[u], xA0); A1 = mk4(hB[u], xA1); }
      acc0 = __builtin_amdgcn_mfma_f32_32x32x16_f16(A0, B, acc0, 0, 0, 0);
      acc1 = __builtin_amdgcn_mfma_f32_32x32x16_f16(A1, B, acc1, 0, 0, 0);
    }
    buf ^= 1;
  }

  // ---- bias: two extra MFMA K-steps (h == 1), B-frags straight from global
  {
    const char* bb = ws + BIAS_OFF + col * 64;
    const h8 B0 = *(const h8*)(bb + hi * 16);
    const h8 B1 = *(const h8*)(bb + 32 + hi * 16);
    acc0 = __builtin_amdgcn_mfma_f32_32x32x16_f16(pk4(xA0), B0, acc0, 0, 0, 0);
    acc1 = __builtin_amdgcn_mfma_f32_32x32x16_f16(pk4(xA1), B0, acc1, 0, 0, 0);
    acc0 = __builtin_amdgcn_mfma_f32_32x32x16_f16(pk4(xB0), B1, acc0, 0, 0, 0);
    acc1 = __builtin_amdgcn_mfma_f32_32x32x16_f16(pk4(xB1), B1, acc1, 0, 0, 0);
  }

  // ---- scatter: C/D layout col=lane&31, row=(r&3)+8*(r>>2)+4*hi
#pragma unroll
  for (int r = 0; r < 16; ++r) {
    const int row = (r & 3) + 8 * (r >> 2) + 4 * hi;
    const int rcv0 = rcv_lds[wid * 64 + row];
    if (rcv0 >= 0) atomicAdd(out + (size_t)rcv0 * 32 + col, acc0[r]);
    const int rcv1 = rcv_lds[wid * 64 + 32 + row];
    if (rcv1 >= 0) atomicAdd(out + (size_t)rcv1 * 32 + col, acc1[r]);
  }
}

extern "C" void kernel_launch(void* const* d_in, const int* in_sizes, int n_in,
                              void* d_out, int out_size, void* d_ws, size_t ws_size,
                              hipStream_t stream) {
  const float* x         = (const float*)d_in[0];
  const int*   senders   = (const int*)d_in[1];
  const int*   receivers = (const int*)d_in[2];
  const float* edge_attr = (const float*)d_in[3];
  const float* W1        = (const float*)d_in[4];
  const float* b1        = (const float*)d_in[5];
  const float* W2        = (const float*)d_in[6];
  const float* b2        = (const float*)d_in[7];
  float* out = (float*)d_out;
  char*  ws  = (char*)d_ws;

  (void)hipMemsetAsync(out, 0, (size_t)N_NODES * 32 * sizeof(float), stream);
  prep_w2t<<<262, 256, 0, stream>>>(W2, b2, W1, b1, ws);
  nnconv_main<<<(E_EDGES + BE - 1) / BE, NT, 0, stream>>>(
      x, senders, receivers, edge_attr, ws, out);
}

// Round 10
// 100.616 us; speedup vs baseline: 1.3521x; 1.3521x over previous
//
#include <hip/hip_runtime.h>
#include <hip/hip_bf16.h>

#define E_EDGES 300000
#define N_NODES 50000
#define BE 256              // edges per block (4 waves x 64)
#define NT 256
#define KC 256              // K-depth per chunk (of 4096)
#define NCHUNK 16
#define CHUNK_BYTES 16384   // 32 v * 256 k * 2B
#define BIAS_OFF 262144     // b2 image (2 KB)

typedef _Float16 h2 __attribute__((ext_vector_type(2)));
typedef _Float16 h8 __attribute__((ext_vector_type(8)));
typedef float f32x16 __attribute__((ext_vector_type(16)));

static __device__ __forceinline__ unsigned short f2h(float f) {
  _Float16 h = (_Float16)f;
  return __builtin_bit_cast(unsigned short, h);
}
static __device__ __forceinline__ h2 cvt2(float a, float b) {
  auto r = __builtin_amdgcn_cvt_pkrtz(a, b);
  return __builtin_bit_cast(h2, r);
}
static __device__ __forceinline__ h2 bcu(unsigned u) { return __builtin_bit_cast(h2, u); }
static __device__ __forceinline__ h2 dup_lo(unsigned u) {
  h2 p = bcu(u); return (h2){p[0], p[0]};
}
static __device__ __forceinline__ h2 dup_hi(unsigned u) {
  h2 p = bcu(u); return (h2){p[1], p[1]};
}
// A-fragment = hd (broadcast h pair) * 4 packed x pairs -> 4 v_pk_mul_f16
static __device__ __forceinline__ h8 mk4(h2 hd, const h2* p) {
  h2 m0 = hd * p[0], m1 = hd * p[1], m2 = hd * p[2], m3 = hd * p[3];
  return (h8){m0[0], m0[1], m1[0], m1[1], m2[0], m2[1], m3[0], m3[1]};
}
static __device__ __forceinline__ h8 pk4(const h2* p) {
  return (h8){p[0][0], p[0][1], p[1][0], p[1][1], p[2][0], p[2][1], p[3][0], p[3][1]};
}

// ---------------------------------------------------------------------------
// Prep: W2 (viewed flat as (4096,32) row-major) -> f16, transposed to
// [v][klocal] per 256-deep chunk, XOR-swizzled ((v&31)<<4 on 16B granules,
// bijective within 512B rows -> conflict-free), linear images in ws.
// Bias b2 -> [v][w] f16 image at BIAS_OFF.
// ---------------------------------------------------------------------------
__global__ void prep_w2t(const float* __restrict__ W2, const float* __restrict__ b2,
                         char* __restrict__ ws) {
  int tid = blockIdx.x * 256 + threadIdx.x;
  if (tid < 65536) {                  // 16 chunks * 32 v * 128 k-pairs
    int c   = tid >> 12;
    int rem = tid & 4095;
    int v   = rem >> 7;               // 0..31
    int kp  = rem & 127;              // k-pair within chunk
    int kg2 = c * KC + kp * 2;        // global K index
    unsigned u = (unsigned)f2h(W2[(size_t)kg2 * 32 + v]) |
                 ((unsigned)f2h(W2[(size_t)(kg2 + 1) * 32 + v]) << 16);
    int off = c * CHUNK_BYTES + v * 512 + ((kp * 4) ^ ((v & 31) << 4));
    *(unsigned*)(ws + off) = u;
  } else if (tid < 66048) {           // bias: 32 v * 16 w-pairs
    int i  = tid - 65536;
    int v  = i & 31;
    int wp = i >> 5;
    int w  = wp * 2;
    unsigned u = (unsigned)f2h(b2[w * 32 + v]) |
                 ((unsigned)f2h(b2[(w + 1) * 32 + v]) << 16);
    *(unsigned*)(ws + BIAS_OFF + v * 64 + wp * 4) = u;
  }
}

// ---------------------------------------------------------------------------
// Fused main (R3 skeleton + h-PIPELINING): per-chunk h recompute is done ONE
// CHUNK AHEAD so its scalar-load/f32-FMA/shfl chain overlaps the MFMA cluster
// of the current chunk instead of serializing in front of it.
// ---------------------------------------------------------------------------
__launch_bounds__(NT, 4)
__global__ void nnconv_main(const float* __restrict__ x,
                            const int* __restrict__ senders,
                            const int* __restrict__ receivers,
                            const float* __restrict__ edge_attr,
                            const float* __restrict__ W1,
                            const float* __restrict__ b1,
                            const char* __restrict__ ws,
                            float* __restrict__ out) {
  __shared__ __align__(16) char w2t[2][CHUNK_BYTES];
  __shared__ int rcv_lds[BE];

  const int t    = threadIdx.x;
  const int wid  = t >> 6;
  const int lane = t & 63;
  const int col  = lane & 31;
  const int hi   = lane >> 5;
  const int E0   = blockIdx.x * BE;

  // ---- issue async stage of chunk 0 (earliest)
  {
#pragma unroll
    for (int it = 0; it < 4; ++it)
      __builtin_amdgcn_global_load_lds(
          (const __attribute__((address_space(1))) void*)(ws + it * 4096 + t * 16),
          (__attribute__((address_space(3))) void*)(&w2t[0][0] + it * 4096 + t * 16), 16, 0, 0);
  }

  rcv_lds[t] = (E0 + t < E_EDGES) ? receivers[E0 + t] : -1;

  // ---- own edge attributes (for h recompute; thread t owns edge E0+t)
  const int ge_own = min(E0 + t, E_EDGES - 1);
  const float2* eap = (const float2*)(edge_attr + (size_t)ge_own * 6);
  const float2 ea01 = eap[0], ea23 = eap[1], ea45 = eap[2];
  const float ev[6] = {ea01.x, ea01.y, ea23.x, ea23.y, ea45.x, ea45.y};

  // ---- h recompute for chunk c -> broadcast to this lane's two edges
  //      (scalar f32 W1/b1 loads -> SMEM queue; shfl = ds_bpermute)
  auto compute_h = [&](int c, h2* dA, h2* dB) {
    float hv[8];
    const float* bp = b1 + c * 8;
    const float4 b0 = *(const float4*)bp, b4 = *(const float4*)(bp + 4);
    hv[0] = b0.x; hv[1] = b0.y; hv[2] = b0.z; hv[3] = b0.w;
    hv[4] = b4.x; hv[5] = b4.y; hv[6] = b4.z; hv[7] = b4.w;
#pragma unroll
    for (int d = 0; d < 6; ++d) {
      const float* wp = W1 + d * 128 + c * 8;
      const float4 w0 = *(const float4*)wp, w4 = *(const float4*)(wp + 4);
      hv[0] += ev[d] * w0.x; hv[1] += ev[d] * w0.y;
      hv[2] += ev[d] * w0.z; hv[3] += ev[d] * w0.w;
      hv[4] += ev[d] * w4.x; hv[5] += ev[d] * w4.y;
      hv[6] += ev[d] * w4.z; hv[7] += ev[d] * w4.w;
    }
    unsigned hp[4];
#pragma unroll
    for (int q = 0; q < 4; ++q)
      hp[q] = __builtin_bit_cast(unsigned,
                cvt2(fmaxf(hv[q * 2], 0.f), fmaxf(hv[q * 2 + 1], 0.f)));
#pragma unroll
    for (int q = 0; q < 4; ++q) {
      const unsigned ua = __shfl(hp[q], col);
      const unsigned ub = __shfl(hp[q], col + 32);
      dA[q * 2] = dup_lo(ua); dA[q * 2 + 1] = dup_hi(ua);
      dB[q * 2] = dup_lo(ub); dB[q * 2 + 1] = dup_hi(ub);
    }
  };

  // ---- gather x_j slices for this lane's two edge rows, convert to f16
  const int el0 = wid * 64 + col;
  const int el1 = el0 + 32;
  const int ge0 = min(E0 + el0, E_EDGES - 1);
  const int ge1 = min(E0 + el1, E_EDGES - 1);
  const float* row0 = x + (size_t)senders[ge0] * 32;
  const float* row1 = x + (size_t)senders[ge1] * 32;
  float4 fa, fb;
  fa = *(const float4*)(row0 + hi * 8);      fb = *(const float4*)(row0 + hi * 8 + 4);
  const h2 xA0[4] = {cvt2(fa.x, fa.y), cvt2(fa.z, fa.w), cvt2(fb.x, fb.y), cvt2(fb.z, fb.w)};
  fa = *(const float4*)(row0 + 16 + hi * 8); fb = *(const float4*)(row0 + 16 + hi * 8 + 4);
  const h2 xB0[4] = {cvt2(fa.x, fa.y), cvt2(fa.z, fa.w), cvt2(fb.x, fb.y), cvt2(fb.z, fb.w)};
  fa = *(const float4*)(row1 + hi * 8);      fb = *(const float4*)(row1 + hi * 8 + 4);
  const h2 xA1[4] = {cvt2(fa.x, fa.y), cvt2(fa.z, fa.w), cvt2(fb.x, fb.y), cvt2(fb.z, fb.w)};
  fa = *(const float4*)(row1 + 16 + hi * 8); fb = *(const float4*)(row1 + 16 + hi * 8 + 4);
  const h2 xB1[4] = {cvt2(fa.x, fa.y), cvt2(fa.z, fa.w), cvt2(fb.x, fb.y), cvt2(fb.z, fb.w)};

  // ---- h for chunk 0 (the only serial h phase)
  h2 hdA[8], hdB[8];
  compute_h(0, hdA, hdB);

  __syncthreads();   // rcv + chunk0 (barrier drains vmcnt) ready

  f32x16 acc0 = {};
  f32x16 acc1 = {};
  const int swB = (col & 31) << 4;
  int buf = 0;

#pragma unroll 1
  for (int c = 0; c < NCHUNK; ++c) {
    if (c + 1 < NCHUNK) {   // prefetch next chunk into other buffer
      const char* g = ws + (c + 1) * CHUNK_BYTES;
      char* l = &w2t[buf ^ 1][0];
#pragma unroll
      for (int it = 0; it < 4; ++it)
        __builtin_amdgcn_global_load_lds(
            (const __attribute__((address_space(1))) void*)(g + it * 4096 + t * 16),
            (__attribute__((address_space(3))) void*)(l + it * 4096 + t * 16), 16, 0, 0);
    }

    // ---- h for chunk c+1 (independent of this chunk's MFMAs -> the
    //      scheduler interleaves it into the MFMA cluster below)
    h2 hdAn[8], hdBn[8];
    if (c + 1 < NCHUNK) compute_h(c + 1, hdAn, hdBn);

    // ---- 16 K-steps over this chunk using h computed LAST iteration
    const char* Bb = &w2t[buf][0] + col * 512;
#pragma unroll
    for (int s = 0; s < 16; ++s) {
      const h8 B = *(const h8*)(Bb + ((s * 32 + hi * 16) ^ swB));
      const int kq = s >> 1;
      h8 A0, A1;
      if (s & 1) { A0 = mk4(hdA[kq], xB0); A1 = mk4(hdB[kq], xB1); }
      else       { A0 = mk4(hdA[kq], xA0); A1 = mk4(hdB[kq], xA1); }
      acc0 = __builtin_amdgcn_mfma_f32_32x32x16_f16(A0, B, acc0, 0, 0, 0);
      acc1 = __builtin_amdgcn_mfma_f32_32x32x16_f16(A1, B, acc1, 0, 0, 0);
    }
    __syncthreads();   // drains prefetch + protects buffer reuse

    if (c + 1 < NCHUNK) {
#pragma unroll
      for (int q = 0; q < 8; ++q) { hdA[q] = hdAn[q]; hdB[q] = hdBn[q]; }
    }
    buf ^= 1;
  }

  // ---- bias: two extra MFMA K-steps (h == 1), B-frags straight from global
  {
    const char* bb = ws + BIAS_OFF + col * 64;
    const h8 B0 = *(const h8*)(bb + hi * 16);
    const h8 B1 = *(const h8*)(bb + 32 + hi * 16);
    acc0 = __builtin_amdgcn_mfma_f32_32x32x16_f16(pk4(xA0), B0, acc0, 0, 0, 0);
    acc1 = __builtin_amdgcn_mfma_f32_32x32x16_f16(pk4(xA1), B0, acc1, 0, 0, 0);
    acc0 = __builtin_amdgcn_mfma_f32_32x32x16_f16(pk4(xB0), B1, acc0, 0, 0, 0);
    acc1 = __builtin_amdgcn_mfma_f32_32x32x16_f16(pk4(xB1), B1, acc1, 0, 0, 0);
  }

  // ---- scatter: C/D layout col=lane&31, row=(r&3)+8*(r>>2)+4*hi
#pragma unroll
  for (int r = 0; r < 16; ++r) {
    const int row = (r & 3) + 8 * (r >> 2) + 4 * hi;
    const int rcv0 = rcv_lds[wid * 64 + row];
    if (rcv0 >= 0) atomicAdd(out + (size_t)rcv0 * 32 + col, acc0[r]);
    const int rcv1 = rcv_lds[wid * 64 + 32 + row];
    if (rcv1 >= 0) atomicAdd(out + (size_t)rcv1 * 32 + col, acc1[r]);
  }
}

extern "C" void kernel_launch(void* const* d_in, const int* in_sizes, int n_in,
                              void* d_out, int out_size, void* d_ws, size_t ws_size,
                              hipStream_t stream) {
  const float* x         = (const float*)d_in[0];
  const int*   senders   = (const int*)d_in[1];
  const int*   receivers = (const int*)d_in[2];
  const float* edge_attr = (const float*)d_in[3];
  const float* W1        = (const float*)d_in[4];
  const float* b1        = (const float*)d_in[5];
  const float* W2        = (const float*)d_in[6];
  const float* b2        = (const float*)d_in[7];
  float* out = (float*)d_out;
  char*  ws  = (char*)d_ws;

  (void)hipMemsetAsync(out, 0, (size_t)N_NODES * 32 * sizeof(float), stream);
  prep_w2t<<<259, 256, 0, stream>>>(W2, b2, ws);
  nnconv_main<<<(E_EDGES + BE - 1) / BE, NT, 0, stream>>>(
      x, senders, receivers, edge_attr, W1, b1, ws, out);
}